// Round 8
// baseline (500.417 us; speedup 1.0000x reference)
//
#include <hip/hip_runtime.h>
#include <hip/hip_bf16.h>
#include <hip/hip_cooperative_groups.h>
#include <math.h>

namespace cg = cooperative_groups;

// Problem constants
#define B_N 65536
#define G_N 6
#define IN_N 512
#define F_N 256
#define O_N 18

// Sort constants
#define NB 256     // histogram chunks (B_N / 256)
#define CHUNK 256

// Fused tiling: 32 sorted rows per tile, full N=256, 8 waves.
// TBM=32: ~72 unified regs (40 VGPR + 32 AGPR) -> 6 waves/EU, 3 blocks/CU.
// TBM=64 needs ~128 regs -> spills (R2/R3/R5: WRITE_SIZE 479/45/94 MB).
#define TBM 32
#define MAXT (B_N / TBM + G_N)   // 2054

typedef __bf16 bf16x8 __attribute__((ext_vector_type(8)));
typedef float f32x4 __attribute__((ext_vector_type(4)));

// ---- workspace layout (bytes) ----
#define WS_BC     0
#define WS_BOFF   8192
#define WS_DESC   16512                         // 2054*12 = 24648 bytes
#define WS_W1F    65536                         // 6 * 256KB = 1572864
#define WS_W2F    (WS_W1F + 1572864)            // 128KB
#define WS_WQT    (WS_W2F + 131072)             // 110592
#define WS_PERM   4194304

// RNE f32->bf16 pair via v_cvt_pk_bf16_f32.
__device__ __forceinline__ unsigned packcvt(float a, float b) {
    __hip_bfloat162 h = __float22bfloat162_rn(float2{a, b});
    union { __hip_bfloat162 h; unsigned u; } c; c.h = h; return c.u;
}
__device__ __forceinline__ bf16x8 asbf(uint4 u) {
    union { uint4 u; bf16x8 b; } c; c.u = u; return c.b;
}
__device__ __forceinline__ float fast_tanh(float x) {
    float e = __expf(2.0f * x);
    return 1.0f - 2.0f / (e + 1.0f);
}

// ---- weight pack unit (one 128-thread sub-block of the old k_pack_all grid) ----
// sb in [0,896): kf = sb&15, w = (sb>>4)&7, z = sb>>7.
// z<6: pack W1[z]; z==6 && kf<8: pack W2; z==6 && kf>=8: transpose Wq.
__device__ __forceinline__ void pack_unit(int sb, int tl,
    const float* W1, const float* W2, const float* Wq,
    unsigned short* W1f, unsigned short* W2f, float* WqT) {
    int kf = sb & 15, w = (sb >> 4) & 7, z = sb >> 7;
    if (z == 6 && kf >= 8) {
        int tid = ((kf - 8) * 8 + w) * 128 + tl;   // 0..8191
        for (int e = tid; e < G_N * O_N * F_N; e += 8192) {
            int f = e & (F_N - 1);
            int go = e >> 8;
            int g = go / O_N, o = go - g * O_N;
            WqT[e] = Wq[((long)g * F_N + f) * O_N + o];
        }
        return;
    }
    const float* src;
    unsigned short* dst;
    int kfTot;
    if (z < 6) { src = W1 + (long)z * IN_N * F_N; dst = W1f + (long)z * IN_N * F_N; kfTot = 16; }
    else       { src = W2; dst = W2f; kfTot = 8; }
    int f = tl >> 6, l = tl & 63;
    int lrow = l & 15, q = l >> 4;
    int n = w * 32 + f * 16 + lrow;
    int k0 = kf * 32 + q * 8;
    const float* s = src + (long)k0 * F_N + n;
    unsigned o[4];
#pragma unroll
    for (int j = 0; j < 4; j++)
        o[j] = packcvt(s[(2 * j) * F_N], s[(2 * j + 1) * F_N]);
    unsigned short* d = dst + ((((long)w * kfTot + kf) * 2 + f) * 64 + l) * 8;
    uint4 v = { o[0], o[1], o[2], o[3] };
    *(uint4*)d = v;
}

// ---------- ONE cooperative kernel: {hist | pack} -> prefix -> scatter -> persistent fused ----------
// Launches 5 -> 1 (total - k_fused has been ~155-165us across all rounds; per-dispatch
// overhead ~4.5us, prep kernels serialized). hist and pack overlap in phase A.
// Fused body is R7's verbatim in a stride-grid persistent loop at the same 3 blocks/CU
// residency (grid = min(768, occupancy*256)). Cross-iteration LDS reuse is safe:
// >=2 barriers between any writer and the prior reader of each buffer.
// Reference quirk: Q-head uses idx[pos]/action[pos] (original-order arrays at the
// sorted position); output lands at position pos.
__global__ __launch_bounds__(512, 6) void k_mega(
    const float* state, const int* action, const int* idx,
    const float* W1, const float* b1, const float* W2, const float* b2,
    const float* Wq, const float* bqv,
    int* bc, int* boff, int* desc, int* perm,
    unsigned short* W1f, unsigned short* W2f, float* WqT,
    float* out) {

    cg::grid_group grid = cg::this_grid();
    int bid = blockIdx.x, nb = gridDim.x;
    int t = threadIdx.x;

    __shared__ __align__(16) unsigned short smA[TBM * 512];   // 32 KB A tile (sort scratch overlay)
    __shared__ __align__(16) unsigned short smH[TBM * 256];   // 16 KB H1
    __shared__ float partial[TBM][9];
    __shared__ int gq[TBM], actv[TBM];
    int* scratch = (int*)smA;

    // ================= phase A: hist (blocks < NB) + pack (all blocks, strided) =================
    if (bid < NB) {
        if (t < G_N) scratch[t] = 0;
        __syncthreads();
        if (t < CHUNK) atomicAdd(&scratch[idx[bid * CHUNK + t]], 1);
        __syncthreads();
        if (t < G_N) bc[bid * G_N + t] = scratch[t];
    }
    for (int sb = bid * 4 + (t >> 7); sb < 896; sb += nb * 4)
        pack_unit(sb, t & 127, W1, W2, Wq, W1f, W2f, WqT);
    grid.sync();

    // ================= phase B: prefix + tile descriptors (block 0) =================
    if (bid == 0) {
        int* sbc    = scratch;                 // 1536 ints
        int* tot    = scratch + NB * G_N;      // 6
        int* stt    = tot + G_N;               // 6
        int* tstart = stt + G_N;               // 7
        for (int i = t; i < NB * G_N; i += 512) sbc[i] = bc[i];
        __syncthreads();
        if (t < 256) {
            int w = t >> 6, l = t & 63;
            for (int g = w; g < G_N; g += 4) {
                int v[4]; int s = 0;
#pragma unroll
                for (int j = 0; j < 4; j++) { v[j] = sbc[(l * 4 + j) * G_N + g]; s += v[j]; }
                int inc = s;
#pragma unroll
                for (int o = 1; o < 64; o <<= 1) { int x = __shfl_up(inc, o, 64); if (l >= o) inc += x; }
                int run = inc - s;   // exclusive prefix
                if (l == 63) tot[g] = inc;
#pragma unroll
                for (int j = 0; j < 4; j++) { sbc[(l * 4 + j) * G_N + g] = run; run += v[j]; }
            }
        }
        __syncthreads();
        if (t == 0) {
            int acc = 0;
            for (int g = 0; g < G_N; g++) { stt[g] = acc; acc += tot[g]; }
            int nt = 0;
            for (int g = 0; g < G_N; g++) { tstart[g] = nt; nt += (tot[g] + TBM - 1) / TBM; }
            tstart[G_N] = nt;
        }
        __syncthreads();
        for (int i = t; i < NB * G_N; i += 512) boff[i] = sbc[i] + stt[i % G_N];
        int nt = tstart[G_N];
        for (int i = t; i < MAXT; i += 512) {
            int gd = 0, r0 = 0, nr = 0;
            if (i < nt) {
                int g = 0;
                while (g < G_N - 1 && i >= tstart[g + 1]) g++;
                int k = i - tstart[g];
                r0 = stt[g] + k * TBM;
                int rem = tot[g] - k * TBM;
                nr = rem < TBM ? rem : TBM;
                gd = g;
            }
            desc[i * 3 + 0] = gd; desc[i * 3 + 1] = r0; desc[i * 3 + 2] = nr;
        }
    }
    grid.sync();

    // ================= phase C: stable scatter (blocks < NB) =================
    if (bid < NB) {
        int* wcnt = scratch;        // [4][G_N]
        int* base = scratch + 24;   // [G_N]
        bool act = t < CHUNK;
        int w = t >> 6, l = t & 63;
        int g = 0, rank = 0;
        if (act) {
            g = idx[bid * CHUNK + t];
            for (int gg2 = 0; gg2 < G_N; gg2++) {
                unsigned long long m = __ballot(g == gg2);
                if (g == gg2) rank = __popcll(m & ((1ull << l) - 1ull));
                if (l == 0) wcnt[w * G_N + gg2] = __popcll(m);
            }
        }
        if (t < G_N) base[t] = boff[bid * G_N + t];
        __syncthreads();
        if (act) {
            int off = base[g] + rank;
            for (int ww = 0; ww < w; ww++) off += wcnt[ww * G_N + g];
            perm[off] = bid * CHUNK + t;
        }
    }
    grid.sync();

    // ================= phase D: persistent fused loop (R7 body) =================
    const char* w1f = (const char*)W1f;
    const char* w2f = (const char*)W2f;
    const float* wqt = WqT;

    int w = t >> 6, l = t & 63;
    int lrow = l & 15, q = l >> 4;
    int x0 = lrow & 7;

    for (int td = bid; td < MAXT; td += nb) {
        int g = desc[td * 3 + 0], row0 = desc[td * 3 + 1], nr = desc[td * 3 + 2];
        if (nr == 0) continue;   // trailing pads only; block-uniform

        // ---- issue first B loads early ----
        const char* B1 = w1f + (((long)g * 8 + w) << 15) + l * 16;
        uint4 nb0 = *(const uint4*)(B1);
        uint4 nb1 = *(const uint4*)(B1 + 1024);

        if (t < TBM) {
            int pos = row0 + t; if (pos > B_N - 1) pos = B_N - 1;
            gq[t] = idx[pos];        // ORIGINAL-order idx at sorted position
            actv[t] = action[pos];   // ORIGINAL-order action at sorted position
        }

        // ---- stage A: 16 threads/row, 8x(float4 load + cvt_pk + swizzled ds_write_b64) ----
        {
            int m = t >> 4, s = t & 15;
            int pr = row0 + m; if (pr > B_N - 1) pr = B_N - 1;
            const float* src = state + (long)perm[pr] * IN_N + s * 4;
            int cb = s >> 1, h = s & 1, mx = m & 7;
            char* rowbase = (char*)smA + m * 1024 + h * 8;
#pragma unroll
            for (int j = 0; j < 8; j++) {
                float4 v = *(const float4*)(src + j * 64);
                uint2 p = { packcvt(v.x, v.y), packcvt(v.z, v.w) };
                int c = (cb + j * 8) ^ mx;
                *(uint2*)(rowbase + c * 16) = p;
            }
        }
        __syncthreads();   // B1: A ready

        // ---- phase 1: H1 = sigmoid(A @ W1[g] + b1[g]), K=512 ----
        const char* ar[2];
#pragma unroll
        for (int i = 0; i < 2; i++) ar[i] = (const char*)smA + (i * 16 + lrow) * 1024;

        f32x4 acc[2][2];
#pragma unroll
        for (int i = 0; i < 2; i++)
#pragma unroll
            for (int j = 0; j < 2; j++) acc[i][j] = (f32x4){0.f, 0.f, 0.f, 0.f};

#pragma unroll
        for (int kf = 0; kf < 16; kf++) {
            uint4 cb0 = nb0, cb1 = nb1;
            if (kf < 15) {
                nb0 = *(const uint4*)(B1 + (kf + 1) * 2048);
                nb1 = *(const uint4*)(B1 + (kf + 1) * 2048 + 1024);
            }
            int c = ((kf * 4 + q) ^ x0) * 16;
            bf16x8 af[2];
#pragma unroll
            for (int i = 0; i < 2; i++) af[i] = *(const bf16x8*)(ar[i] + c);
            bf16x8 b0 = asbf(cb0), b1v = asbf(cb1);
#pragma unroll
            for (int i = 0; i < 2; i++) {
                acc[i][0] = __builtin_amdgcn_mfma_f32_16x16x32_bf16(af[i], b0, acc[i][0], 0, 0, 0);
                acc[i][1] = __builtin_amdgcn_mfma_f32_16x16x32_bf16(af[i], b1v, acc[i][1], 0, 0, 0);
            }
        }
        // NO barrier: epilogue writes smH (separate region); smA reads complete
        // in-wave; next-iter smA writes are separated by B3+B4.

        // ---- prefetch first W2 fragments ----
        const char* B2 = w2f + ((long)w << 14) + l * 16;
        uint4 m0 = *(const uint4*)(B2);
        uint4 m1 = *(const uint4*)(B2 + 1024);

        // ---- epilogue 1: sigmoid -> cvt_pk bf16 -> swizzled LDS H1[32][256] ----
        {
            int col0 = w * 32 + lrow;
            float bias0 = b1[g * F_N + col0];
            float bias1 = b1[g * F_N + col0 + 16];
            int cc = col0 >> 3, cb2 = (col0 & 7) * 2;
#pragma unroll
            for (int i = 0; i < 2; i++)
#pragma unroll
                for (int r = 0; r < 4; r++) {
                    int row = i * 16 + q * 4 + r;
                    float v0 = acc[i][0][r] + bias0;
                    float v1 = acc[i][1][r] + bias1;
                    float sg0 = 1.0f / (1.0f + __expf(-v0));
                    float sg1 = 1.0f / (1.0f + __expf(-v1));
                    unsigned pk = packcvt(sg0, sg1);
                    int rx = row & 7;
                    char* base = (char*)smH + row * 512 + cb2;
                    *(unsigned short*)(base + ((cc)     ^ rx) * 16) = (unsigned short)pk;
                    *(unsigned short*)(base + ((cc + 2) ^ rx) * 16) = (unsigned short)(pk >> 16);
                }
        }
        __syncthreads();   // B3: H1 ready

        // ---- phase 2: HF = relu(H1 @ W2 + b2), K=256 ----
        const char* hr[2];
#pragma unroll
        for (int i = 0; i < 2; i++) hr[i] = (const char*)smH + (i * 16 + lrow) * 512;

        f32x4 acc2[2][2];
#pragma unroll
        for (int i = 0; i < 2; i++)
#pragma unroll
            for (int j = 0; j < 2; j++) acc2[i][j] = (f32x4){0.f, 0.f, 0.f, 0.f};

#pragma unroll
        for (int kf = 0; kf < 8; kf++) {
            uint4 c0 = m0, c1 = m1;
            if (kf < 7) {
                m0 = *(const uint4*)(B2 + (kf + 1) * 2048);
                m1 = *(const uint4*)(B2 + (kf + 1) * 2048 + 1024);
            }
            int c = ((kf * 4 + q) ^ x0) * 16;
            bf16x8 af[2];
#pragma unroll
            for (int i = 0; i < 2; i++) af[i] = *(const bf16x8*)(hr[i] + c);
            bf16x8 b0 = asbf(c0), b1v = asbf(c1);
#pragma unroll
            for (int i = 0; i < 2; i++) {
                acc2[i][0] = __builtin_amdgcn_mfma_f32_16x16x32_bf16(af[i], b0, acc2[i][0], 0, 0, 0);
                acc2[i][1] = __builtin_amdgcn_mfma_f32_16x16x32_bf16(af[i], b1v, acc2[i][1], 0, 0, 0);
            }
        }

        // ---- final: per-row dot with WqT[idx[pos]][action[pos]][:], wave-partial reduce ----
        {
            int col0 = w * 32 + lrow;
            float bias0 = b2[col0], bias1 = b2[col0 + 16];
#pragma unroll
            for (int i = 0; i < 2; i++)
#pragma unroll
                for (int r = 0; r < 4; r++) {
                    int row = i * 16 + q * 4 + r;
                    const float* wp = wqt + ((long)gq[row] * O_N + actv[row]) * F_N;
                    float v0 = fmaxf(acc2[i][0][r] + bias0, 0.0f);
                    float v1 = fmaxf(acc2[i][1][r] + bias1, 0.0f);
                    float s2 = v0 * wp[col0] + v1 * wp[col0 + 16];
                    s2 += __shfl_xor(s2, 1, 64);
                    s2 += __shfl_xor(s2, 2, 64);
                    s2 += __shfl_xor(s2, 4, 64);
                    s2 += __shfl_xor(s2, 8, 64);
                    if (lrow == 0) partial[row][w] = s2;
                }
        }
        __syncthreads();   // B4: partials ready
        if (t < TBM && t < nr) {
            float s2 = 0.f;
#pragma unroll
            for (int ww = 0; ww < 8; ww++) s2 += partial[t][ww];
            out[row0 + t] = fast_tanh(s2 + bqv[gq[t] * O_N + actv[t]]);
        }
    }
}

extern "C" void kernel_launch(void* const* d_in, const int* in_sizes, int n_in,
                              void* d_out, int out_size, void* d_ws, size_t ws_size,
                              hipStream_t stream) {
    const float* state  = (const float*)d_in[0];
    const int*   action = (const int*)d_in[1];
    const int*   idx    = (const int*)d_in[2];
    const float* W1     = (const float*)d_in[3];
    const float* b1     = (const float*)d_in[4];
    const float* W2     = (const float*)d_in[5];
    const float* b2     = (const float*)d_in[6];
    const float* Wq     = (const float*)d_in[7];
    const float* bq     = (const float*)d_in[8];
    float* out = (float*)d_out;

    char* ws = (char*)d_ws;
    int* bc      = (int*)(ws + WS_BC);
    int* boff    = (int*)(ws + WS_BOFF);
    int* desc    = (int*)(ws + WS_DESC);
    unsigned short* W1f = (unsigned short*)(ws + WS_W1F);
    unsigned short* W2f = (unsigned short*)(ws + WS_W2F);
    float* WqT   = (float*)(ws + WS_WQT);
    int* perm    = (int*)(ws + WS_PERM);

    int maxb = 0;
    if (hipOccupancyMaxActiveBlocksPerMultiprocessor(&maxb, k_mega, 512, 0) != hipSuccess || maxb < 1)
        maxb = 1;
    int grid = maxb * 256;
    if (grid > 768) grid = 768;   // 3 blocks/CU by LDS (50.7KB) and launch bounds
    if (grid < NB)  grid = NB;    // hist/scatter need 256 blocks

    void* args[] = {
        (void*)&state, (void*)&action, (void*)&idx,
        (void*)&W1, (void*)&b1, (void*)&W2, (void*)&b2,
        (void*)&Wq, (void*)&bq,
        (void*)&bc, (void*)&boff, (void*)&desc, (void*)&perm,
        (void*)&W1f, (void*)&W2f, (void*)&WqT,
        (void*)&out
    };
    hipLaunchCooperativeKernel((const void*)k_mega, dim3(grid), dim3(512), args, 0, stream);
}